// Round 5
// baseline (1398.124 us; speedup 1.0000x reference)
//
#include <hip/hip_runtime.h>
#include <cmath>

#define B_ 4
#define T_ 4096
#define D_ 1024

typedef __attribute__((ext_vector_type(4))) float f32x4;
typedef __attribute__((ext_vector_type(8))) short s16x8;
typedef unsigned short ushort_t;

__device__ __forceinline__ f32x4 mfma_bf16(s16x8 a, s16x8 b, f32x4 c) {
    return __builtin_amdgcn_mfma_f32_16x16x32_bf16(a, b, c, 0, 0, 0);
}
__device__ __forceinline__ unsigned short f2bf(float f) {
    union { float f; unsigned int u; } v; v.f = f;
    unsigned int r = v.u + 0x7FFFu + ((v.u >> 16) & 1u);
    return (unsigned short)(r >> 16);
}
union U64 { unsigned long long u; unsigned short s[4]; };
union F8 { s16x8 v; unsigned short u[8]; };

// ---------------- kernel 1: repack fp32 weights to bf16 wt[p*16+h][d][i] ----
__global__ __launch_bounds__(256) void k_wtrans(const float* __restrict__ wq,
                                                const float* __restrict__ wk,
                                                const float* __restrict__ wv,
                                                ushort_t* __restrict__ wt) {
    int p = blockIdx.x >> 4;
    int h = blockIdx.x & 15;
    const float* src = (p == 0) ? wq : (p == 1) ? wk : wv;
    ushort_t* dst = wt + (size_t)((p * 16 + h) * 64) * 64;
    for (int idx = threadIdx.x; idx < 64 * 64; idx += 256) {
        int d = idx >> 6, i = idx & 63;
        dst[d * 64 + i] = f2bf(src[i * 1024 + d * 16 + h]);   // w[i][d][h]
    }
}

// ---------------- kernel 2: QKV projection + fused RoPE (v2) ----------------
// block: 256 thr (4 waves) = (b, 32-token chunk), ALL 16 heads.
// x staged coalesced once. Q,K -> [b][h][t][d]; V -> [b][h][d][t]. bf16.
__global__ __launch_bounds__(256) void k_qkv(const float* __restrict__ x,
                                             const ushort_t* __restrict__ wt,
                                             ushort_t* __restrict__ Qt,
                                             ushort_t* __restrict__ Kt,
                                             ushort_t* __restrict__ Vt) {
    int bid = blockIdx.x;
    int b = bid >> 7, tc = bid & 127;
    int t0 = tc * 32;
    int tid = threadIdx.x, w = tid >> 6, lane = tid & 63;
    int quad = lane >> 4, l16 = lane & 15;

    __shared__ ushort_t xh[32 * 1032];   // [t][e], row pad 1032 (2064 B, 8-aligned)

    // ---- stage x tile (coalesced f32x4), convert to bf16 ----
    {
        int ts = tid >> 3, s = tid & 7;
        const float* xrow = x + ((size_t)(b * T_ + t0 + ts)) * D_;
        ushort_t* xl = xh + ts * 1032;
        #pragma unroll
        for (int k = 0; k < 32; ++k) {
            int e = (s + 8 * k) * 4;
            f32x4 v = *(const f32x4*)(xrow + e);
            U64 pk;
            pk.s[0] = f2bf(v.x); pk.s[1] = f2bf(v.y);
            pk.s[2] = f2bf(v.z); pk.s[3] = f2bf(v.w);
            *(unsigned long long*)(xl + e) = pk.u;
        }
    }
    __syncthreads();

    // wave handles head-pairs pr = 2w, 2w+1
    for (int pp = 0; pp < 2; ++pp) {
        int pr = w * 2 + pp;
        int h0 = pr * 2;

        // X fragments for both heads: xf[hh][tt][ic] (A- and B-operand compatible)
        s16x8 xf[2][2][2];
        #pragma unroll
        for (int hh = 0; hh < 2; ++hh)
            #pragma unroll
            for (int tt = 0; tt < 2; ++tt)
                #pragma unroll
                for (int ic = 0; ic < 2; ++ic) {
                    F8 f;
                    #pragma unroll
                    for (int j = 0; j < 8; ++j)
                        f.u[j] = xh[(tt * 16 + l16) * 1032 + (ic * 32 + quad * 8 + j) * 16 + (h0 + hh)];
                    xf[hh][tt][ic] = f.v;
                }

        // ---- V for both heads: C[d][t] = W^T[d][i] X^T[i][t] ----
        #pragma unroll
        for (int hh = 0; hh < 2; ++hh) {
            int h = h0 + hh;
            f32x4 av[4][2];
            #pragma unroll
            for (int dt = 0; dt < 4; ++dt) { av[dt][0] = (f32x4){0,0,0,0}; av[dt][1] = (f32x4){0,0,0,0}; }
            #pragma unroll
            for (int dt = 0; dt < 4; ++dt)
                #pragma unroll
                for (int ic = 0; ic < 2; ++ic) {
                    s16x8 wf = *(const s16x8*)&wt[((size_t)((2 * 16 + h) * 64 + dt * 16 + l16)) * 64 + ic * 32 + quad * 8];
                    av[dt][0] = mfma_bf16(wf, xf[hh][0][ic], av[dt][0]);
                    av[dt][1] = mfma_bf16(wf, xf[hh][1][ic], av[dt][1]);
                }
            #pragma unroll
            for (int dt = 0; dt < 4; ++dt)
                #pragma unroll
                for (int tt = 0; tt < 2; ++tt)
                    #pragma unroll
                    for (int r = 0; r < 4; ++r)
                        Vt[((size_t)(b * 16 + h) * 64 + dt * 16 + quad * 4 + r) * T_ + t0 + tt * 16 + l16] =
                            f2bf(av[dt][tt][r]);
        }

        // ---- Q,K for the pair: C[t][d] = X[t][i] W[i][d] ----
        f32x4 aq[2][2][4], ak[2][2][4];   // [hh][tt][dt]
        #pragma unroll
        for (int hh = 0; hh < 2; ++hh)
            #pragma unroll
            for (int tt = 0; tt < 2; ++tt)
                #pragma unroll
                for (int dt = 0; dt < 4; ++dt) { aq[hh][tt][dt] = (f32x4){0,0,0,0}; ak[hh][tt][dt] = (f32x4){0,0,0,0}; }
        #pragma unroll
        for (int hh = 0; hh < 2; ++hh) {
            int h = h0 + hh;
            #pragma unroll
            for (int dt = 0; dt < 4; ++dt)
                #pragma unroll
                for (int ic = 0; ic < 2; ++ic) {
                    s16x8 wfq = *(const s16x8*)&wt[((size_t)((0 * 16 + h) * 64 + dt * 16 + l16)) * 64 + ic * 32 + quad * 8];
                    s16x8 wfk = *(const s16x8*)&wt[((size_t)((1 * 16 + h) * 64 + dt * 16 + l16)) * 64 + ic * 32 + quad * 8];
                    #pragma unroll
                    for (int tt = 0; tt < 2; ++tt) {
                        aq[hh][tt][dt] = mfma_bf16(xf[hh][tt][ic], wfq, aq[hh][tt][dt]);
                        ak[hh][tt][dt] = mfma_bf16(xf[hh][tt][ic], wfk, ak[hh][tt][dt]);
                    }
                }
        }

        // ---- RoPE: pairs (d,h0)<->(d,h0+1), j = d*8 + pr ----
        #pragma unroll
        for (int tt = 0; tt < 2; ++tt)
            #pragma unroll
            for (int dt = 0; dt < 4; ++dt) {
                int d = dt * 16 + l16;
                float f = exp2f((float)(d * 8 + pr) * -0.02595256324130751f); // -log2(1e4)/512
                #pragma unroll
                for (int r = 0; r < 4; ++r) {
                    float ang = (float)(t0 + tt * 16 + quad * 4 + r) * f;
                    float sn, cs;
                    __sincosf(ang, &sn, &cs);
                    float q0v = aq[0][tt][dt][r], q1v = aq[1][tt][dt][r];
                    aq[0][tt][dt][r] = q0v * cs - q1v * sn;
                    aq[1][tt][dt][r] = q0v * sn + q1v * cs;
                    float k0v = ak[0][tt][dt][r], k1v = ak[1][tt][dt][r];
                    ak[0][tt][dt][r] = k0v * cs - k1v * sn;
                    ak[1][tt][dt][r] = k0v * sn + k1v * cs;
                }
            }

        // ---- store Q,K [b][h][t][d] ----
        #pragma unroll
        for (int hh = 0; hh < 2; ++hh) {
            int h = h0 + hh;
            #pragma unroll
            for (int tt = 0; tt < 2; ++tt)
                #pragma unroll
                for (int dt = 0; dt < 4; ++dt)
                    #pragma unroll
                    for (int r = 0; r < 4; ++r) {
                        size_t off = ((size_t)(b * 16 + h) * T_ + t0 + tt * 16 + quad * 4 + r) * 64 + dt * 16 + l16;
                        Qt[off] = f2bf(aq[hh][tt][dt][r]);
                        Kt[off] = f2bf(ak[hh][tt][dt][r]);
                    }
        }
    }
}

// ---------------- kernel 3: flash attention (v2) ---------------------------
// 512 thr (8 waves), q-tile 32, k-tile 128. Wave: qg = w&1 (16 q-rows),
// kp = w>>1 (32 k-rows). Full-d S per wave (Q frags in 128 VGPRs); tiny
// LDS partials for softmax; PV d-split 128/wave.
__global__ __launch_bounds__(512, 2) void k_attn(const ushort_t* __restrict__ Qt,
                                                 const ushort_t* __restrict__ Kt,
                                                 const ushort_t* __restrict__ Vt,
                                                 float* __restrict__ out) {
    int bid = blockIdx.x;
    int j = bid >> 2, b = bid & 3;
    int qt = (bid < 256) ? (127 - j) : (j - 64);   // heavy-first
    int q0 = qt * 32;
    int tid = threadIdx.x, w = tid >> 6, lane = tid & 63;
    int quad = lane >> 4, l16 = lane & 15;
    int qg = w & 1, kp = w >> 1;

    __shared__ float m_part[32][4];
    __shared__ float l_part[32][4];
    __shared__ float alpha_s[32];
    __shared__ ushort_t P_l[32][136];   // [q][k] k-contig, 272 B rows (16-aligned)

    // Q fragments (loop-invariant, registers): q = q0+qg*16+l16, d = c*32+quad*8
    s16x8 qf[32];
    {
        int tq = q0 + qg * 16 + l16;
        #pragma unroll
        for (int c = 0; c < 32; ++c) {
            int head = c >> 1, d64 = (c & 1) * 32 + quad * 8;
            qf[c] = *(const s16x8*)&Qt[((size_t)(b * 16 + head) * T_ + tq) * 64 + d64];
        }
    }

    f32x4 Y[8][2];
    #pragma unroll
    for (int mt = 0; mt < 8; ++mt) { Y[mt][0] = (f32x4){0,0,0,0}; Y[mt][1] = (f32x4){0,0,0,0}; }

    float m_run = -INFINITY;
    float l_run0 = 0.f, l_run1 = 0.f;
    int qglob = q0 + qg * 16 + l16;
    int nkt = (qt + 4) >> 2;
    const float gamma = 0.03125f;

    for (int it = 0; it < nkt; ++it) {
        int kbase = it << 7;

        // ---- S phase: full-1024-d, 16q x 32k per wave ----
        f32x4 S0 = (f32x4){0,0,0,0}, S1 = (f32x4){0,0,0,0};
        int kt0 = kbase + kp * 32 + l16;
        #pragma unroll
        for (int c = 0; c < 32; ++c) {
            int head = c >> 1, d64 = (c & 1) * 32 + quad * 8;
            const ushort_t* kb = &Kt[(size_t)(b * 16 + head) * T_ * 64 + d64];
            s16x8 kf0 = *(const s16x8*)&kb[(size_t)kt0 * 64];
            s16x8 kf1 = *(const s16x8*)&kb[(size_t)(kt0 + 16) * 64];
            S0 = mfma_bf16(kf0, qf[c], S0);
            S1 = mfma_bf16(kf1, qf[c], S1);
        }

        // ---- scale, mask, patch max ----
        float sv[8];
        float mx = -INFINITY;
        #pragma unroll
        for (int sub = 0; sub < 2; ++sub) {
            int bk = kbase + kp * 32 + sub * 16 + quad * 4;
            #pragma unroll
            for (int r = 0; r < 4; ++r) {
                float s = (sub ? S1[r] : S0[r]) * gamma;
                if (bk + r > qglob) s = -INFINITY;
                sv[sub * 4 + r] = s;
                mx = fmaxf(mx, s);
            }
        }
        mx = fmaxf(mx, __shfl_xor(mx, 16));
        mx = fmaxf(mx, __shfl_xor(mx, 32));
        if (quad == 0) m_part[qg * 16 + l16][kp] = mx;
        __syncthreads();   // barrier A

        // ---- online softmax ----
        f32x4 mp = *(const f32x4*)m_part[qg * 16 + l16];
        float m_tile = fmaxf(fmaxf(mp.x, mp.y), fmaxf(mp.z, mp.w));
        float m_new = fmaxf(m_run, m_tile);
        float alpha = __expf(m_run - m_new);
        m_run = m_new;
        float lsum = 0.f;
        #pragma unroll
        for (int i = 0; i < 8; ++i) {
            float p = __expf(sv[i] - m_new);
            sv[i] = p;
            lsum += p;
        }
        lsum += __shfl_xor(lsum, 16);
        lsum += __shfl_xor(lsum, 32);
        if (quad == 0) l_part[qg * 16 + l16][kp] = lsum;
        if (w == 0 && quad == 0) alpha_s[l16] = alpha;
        if (w == 1 && quad == 0) alpha_s[16 + l16] = alpha;
        #pragma unroll
        for (int sub = 0; sub < 2; ++sub) {
            U64 pk;
            #pragma unroll
            for (int r = 0; r < 4; ++r) pk.s[r] = f2bf(sv[sub * 4 + r]);
            *(unsigned long long*)&P_l[qg * 16 + l16][kp * 32 + sub * 16 + quad * 4] = pk.u;
        }
        __syncthreads();   // barrier B

        // ---- PV phase: Y[32q][128d-slice] += P(32x128) V(128x128d) ----
        float a0 = alpha_s[l16], a1 = alpha_s[16 + l16];
        f32x4 lp0 = *(const f32x4*)l_part[l16];
        f32x4 lp1 = *(const f32x4*)l_part[16 + l16];
        l_run0 = a0 * l_run0 + (lp0.x + lp0.y + lp0.z + lp0.w);
        l_run1 = a1 * l_run1 + (lp1.x + lp1.y + lp1.z + lp1.w);
        if (__ballot(a0 != 1.f) | __ballot(a1 != 1.f)) {
            #pragma unroll
            for (int mt = 0; mt < 8; ++mt) { Y[mt][0] *= a0; Y[mt][1] *= a1; }
        }
        s16x8 pf0[4], pf1[4];
        #pragma unroll
        for (int kc = 0; kc < 4; ++kc) {
            pf0[kc] = *(const s16x8*)&P_l[l16][kc * 32 + quad * 8];
            pf1[kc] = *(const s16x8*)&P_l[16 + l16][kc * 32 + quad * 8];
        }
        #pragma unroll
        for (int mt = 0; mt < 8; ++mt) {
            int dg = w * 128 + mt * 16 + l16;
            int head = dg >> 6, d64 = dg & 63;
            const ushort_t* vb = &Vt[((size_t)(b * 16 + head) * 64 + d64) * T_ + kbase];
            #pragma unroll
            for (int kc = 0; kc < 4; ++kc) {
                s16x8 vf = *(const s16x8*)&vb[kc * 32 + quad * 8];
                Y[mt][0] = mfma_bf16(vf, pf0[kc], Y[mt][0]);
                Y[mt][1] = mfma_bf16(vf, pf1[kc], Y[mt][1]);
            }
        }
    }

    // ---- epilogue: normalize, d -> e = d64*16+head, fp32 store ----
    float inv0 = 1.f / l_run0, inv1 = 1.f / l_run1;
    #pragma unroll
    for (int mt = 0; mt < 8; ++mt)
        #pragma unroll
        for (int r = 0; r < 4; ++r) {
            int dg = w * 128 + mt * 16 + quad * 4 + r;
            int head = dg >> 6, d64 = dg & 63;
            int e = d64 * 16 + head;
            out[(size_t)(b * T_ + q0 + l16) * D_ + e]      = Y[mt][0][r] * inv0;
            out[(size_t)(b * T_ + q0 + 16 + l16) * D_ + e] = Y[mt][1][r] * inv1;
        }
}

extern "C" void kernel_launch(void* const* d_in, const int* in_sizes, int n_in,
                              void* d_out, int out_size, void* d_ws, size_t ws_size,
                              hipStream_t stream) {
    const float* x  = (const float*)d_in[0];
    const float* wq = (const float*)d_in[1];
    const float* wk = (const float*)d_in[2];
    const float* wv = (const float*)d_in[3];
    ushort_t* ws = (ushort_t*)d_ws;

    const size_t WT_ELEMS  = 3 * 16 * 64 * 64;
    const size_t QKV_ELEMS = (size_t)B_ * 16 * T_ * 64;
    const size_t NEED_BYTES = (WT_ELEMS + 3 * QKV_ELEMS) * sizeof(ushort_t);
    if (ws_size < NEED_BYTES) return;

    ushort_t* wt = ws;
    ushort_t* Qt = ws + WT_ELEMS;
    ushort_t* Kt = Qt + QKV_ELEMS;
    ushort_t* Vt = Kt + QKV_ELEMS;
    float* outp = (float*)d_out;

    k_wtrans<<<48, 256, 0, stream>>>(wq, wk, wv, wt);
    k_qkv<<<512, 256, 0, stream>>>(x, wt, Qt, Kt, Vt);
    k_attn<<<512, 512, 0, stream>>>(Qt, Kt, Vt, outp);
}